// Round 16
// baseline (334.819 us; speedup 1.0000x reference)
//
#include <hip/hip_runtime.h>
#include <hip/hip_fp16.h>

// Problem constants
#define BS    8192
#define DIM   256
#define KTOT  16384      // 128x128 codebook
#define SLOTS 256        // candidate slots per sample (8 MB total, aliases T)
#define MARGIN 1.0f

typedef __attribute__((ext_vector_type(8))) _Float16 half8;
typedef __attribute__((ext_vector_type(4))) float f32x4;
typedef unsigned long long u64;

__device__ inline ushort f2h(float f) { return __half_as_ushort(__float2half(f)); }

// async global->LDS, 16B per lane; lds dest = wave-uniform base + lane*16
__device__ inline void gload_lds16(const void* g, void* l) {
    __builtin_amdgcn_global_load_lds(
        (const __attribute__((address_space(1))) unsigned int*)g,
        (__attribute__((address_space(3))) unsigned int*)l, 16, 0, 0);
}

// order-preserving f32 -> u32 map (ascending) and inverse
__device__ inline unsigned int fmap(float f) {
    unsigned int b = __float_as_uint(f);
    return (b & 0x80000000u) ? ~b : (b | 0x80000000u);
}
__device__ inline float unfmap(unsigned int m) {
    return (m & 0x80000000u) ? __uint_as_float(m & 0x7FFFFFFFu)
                             : __uint_as_float(~m);
}

// ---------------------------------------------------------------------------
// prep: merged setup + cvt.  Grid 6144 x 256 (rows 0..24575 == BS+KTOT).
//  - zero S (16 MB), G table, zero cntf, init keys(u32), zero cslot
//  - x,w -> fp16 with XOR-swizzled 32-half windows, + wsq for w rows
__global__ void prep_kernel(const float* __restrict__ x, const float* __restrict__ w,
                            ushort* __restrict__ xf, ushort* __restrict__ wf,
                            float* __restrict__ wsq, float* __restrict__ S,
                            float* __restrict__ G, float* __restrict__ cntf,
                            unsigned int* __restrict__ keys, unsigned int* __restrict__ cslot,
                            const int* __restrict__ itp) {
    int idx = blockIdx.x * 256 + threadIdx.x;
    if (idx < 1048576)     // 4M floats of S
        *(float4*)&S[(size_t)idx * 4] = make_float4(0.f, 0.f, 0.f, 0.f);
    if (idx < KTOT) {
        float itf = (float)itp[0];
        const float START_SIGMA = 64.0f;
        const float TAU = (float)(20.0 / 4.1588830833596715);  // 20 / ln(64)
        float sigma = START_SIGMA * expf(-itf / TAU);
        float d2 = 2.0f * sigma * sigma;
        int i = idx >> 7, j = idx & 127;
        float diff = (float)(i - j);
        G[idx] = expf(-(diff * diff) / d2);
        cntf[idx] = 0.f;
    }
    if (idx < BS) { keys[idx] = 0xFFFFFFFFu; cslot[idx] = 0u; }

    // cvt part: one wave per row
    int wid = threadIdx.x >> 6, lane = threadIdx.x & 63;
    int row = blockIdx.x * 4 + wid;           // 0 .. 24575 exactly
    int h = lane * 4;                         // half index 0..255
    int window = h >> 5, c = (h >> 3) & 3, off = h & 7;
    if (row < BS) {
        int swpos = (window << 5) + (((c ^ ((row >> 1) & 3)) << 3)) + off;
        float4 v = *(const float4*)&x[(size_t)row * DIM + h];
        ushort4 hv;
        hv.x = f2h(v.x); hv.y = f2h(v.y); hv.z = f2h(v.z); hv.w = f2h(v.w);
        *(ushort4*)&xf[(size_t)row * DIM + swpos] = hv;
    } else {
        int r = row - BS;
        int swpos = (window << 5) + (((c ^ ((r >> 1) & 3)) << 3)) + off;
        float4 v = *(const float4*)&w[(size_t)r * DIM + h];
        ushort4 hv;
        hv.x = f2h(v.x); hv.y = f2h(v.y); hv.z = f2h(v.z); hv.w = f2h(v.w);
        *(ushort4*)&wf[(size_t)r * DIM + swpos] = hv;
        float s = v.x * v.x + v.y * v.y + v.z * v.z + v.w * v.w;
        #pragma unroll
        for (int o = 32; o; o >>= 1) s += __shfl_down(s, o, 64);
        if (lane == 0) wsq[r] = s;
    }
}

// ---------------------------------------------------------------------------
// Seed pass: min over 2048 codebook rows (one 128-row k-tile per block).
// XCD-aware swizzle: each XCD gets a contiguous chunk of 128 tiles (2 full
// k-ranges x all m-blocks) so its 4 MB L2 holds the A panel + 2 B panels.
// keys[s] = atomicMin of fmap(seed min).
__global__ __launch_bounds__(256) void bmu_seed_kernel(
    const ushort* __restrict__ xf, const ushort* __restrict__ wf,
    const float* __restrict__ wsq, unsigned int* __restrict__ keys) {
    __shared__ ushort A[128 * 32];   //  8 KB
    __shared__ ushort B[128 * 32];   //  8 KB
    __shared__ float red[128][2];

    int orig = blockIdx.x + blockIdx.y * 64;       // 1024 blocks
    int swz  = (orig & 7) * 128 + (orig >> 3);     // bijective (1024 = 8*128)
    int m0 = (swz & 63) * 128;
    int k0 = (swz >> 6) * 1024;                    // one kt tile: rows k0..k0+127
    int tid = threadIdx.x, w = tid >> 6, lane = tid & 63;
    int wm = (w & 1) * 64, wn = (w >> 1) * 64;
    int lm = lane & 15, quad = lane >> 4;
    int sw = (quad ^ ((lm >> 1) & 3)) * 8;
    int srow = lane >> 2, scol = (lane & 3) * 8;

    f32x4 acc[4][4];
    #pragma unroll
    for (int mi = 0; mi < 4; ++mi)
        #pragma unroll
        for (int ni = 0; ni < 4; ++ni)
            acc[mi][ni] = (f32x4){0.f, 0.f, 0.f, 0.f};

    unsigned abase = (unsigned)(m0 + w * 32 + srow) * DIM + scol;
    unsigned bbase = (unsigned)(k0 + w * 32 + srow) * DIM + scol;
    for (int kb = 0; kb < DIM; kb += 32) {
        unsigned axoff = abase + kb;
        unsigned bxoff = bbase + kb;
        gload_lds16(xf + axoff,             &A[(w * 32) * 32]);
        gload_lds16(xf + axoff + 16u * DIM, &A[(w * 32 + 16) * 32]);
        gload_lds16(wf + bxoff,             &B[(w * 32) * 32]);
        gload_lds16(wf + bxoff + 16u * DIM, &B[(w * 32 + 16) * 32]);
        __syncthreads();
        half8 av[4], bv[4];
        #pragma unroll
        for (int mi = 0; mi < 4; ++mi)
            av[mi] = *(const half8*)&A[(wm + mi * 16 + lm) * 32 + sw];
        #pragma unroll
        for (int ni = 0; ni < 4; ++ni)
            bv[ni] = *(const half8*)&B[(wn + ni * 16 + lm) * 32 + sw];
        #pragma unroll
        for (int mi = 0; mi < 4; ++mi)
            #pragma unroll
            for (int ni = 0; ni < 4; ++ni)
                acc[mi][ni] = __builtin_amdgcn_mfma_f32_16x16x32_f16(
                    av[mi], bv[ni], acc[mi][ni], 0, 0, 0);
        __syncthreads();
    }
    float wsqv[4];
    #pragma unroll
    for (int ni = 0; ni < 4; ++ni) wsqv[ni] = wsq[k0 + wn + ni * 16 + lm];
    #pragma unroll
    for (int mi = 0; mi < 4; ++mi)
        #pragma unroll
        for (int r = 0; r < 4; ++r) {
            float b = 3.4e38f;
            #pragma unroll
            for (int ni = 0; ni < 4; ++ni)
                b = fminf(b, fmaf(-2.0f, acc[mi][ni][r], wsqv[ni]));
            #pragma unroll
            for (int mask = 1; mask < 16; mask <<= 1)
                b = fminf(b, __shfl_xor(b, mask, 64));
            if (lm == 0) red[wm + mi * 16 + quad * 4 + r][w >> 1] = b;
        }
    __syncthreads();
    if (tid < 128)
        atomicMin(&keys[m0 + tid], fmap(fminf(red[tid][0], red[tid][1])));
}

// ---------------------------------------------------------------------------
// Main fused pass: single full fp16 GEMM (2-barrier 32-K steps — the proven
// best structure).  Grid (64, 16): 8 k-tiles/block, 1024 blocks = 4/CU.
// XCD-aware swizzle (same chunking as seed) for L2 locality of the drained
// global_load_lds.  thr = seed(keys) + MARGIN in a 128-entry LDS table.
// Emission: per-SAMPLE slot arrays -- atomicAdd on cslot[s], u32 k payload.
__global__ __launch_bounds__(256) void bmu_fused_kernel(
    const ushort* __restrict__ xf, const ushort* __restrict__ wf,
    const float* __restrict__ wsq, const unsigned int* __restrict__ keys,
    unsigned int* __restrict__ cand, unsigned int* __restrict__ cslot) {
    __shared__ ushort A[128 * 32];   //  8 KB
    __shared__ ushort B[128 * 32];   //  8 KB
    __shared__ float thr_l[128];     //  0.5 KB per-row thresholds

    int orig = blockIdx.x + blockIdx.y * 64;       // 1024 blocks
    int swz  = (orig & 7) * 128 + (orig >> 3);     // bijective (1024 = 8*128)
    int m0 = (swz & 63) * 128;
    int kbase = (swz >> 6) * 1024;                 // 8 k-tiles per block
    int tid = threadIdx.x, w = tid >> 6, lane = tid & 63;
    int wm = (w & 1) * 64, wn = (w >> 1) * 64;
    int lm = lane & 15, quad = lane >> 4;
    int sw = (quad ^ ((lm >> 1) & 3)) * 8;
    int srow = lane >> 2, scol = (lane & 3) * 8;

    if (tid < 128) thr_l[tid] = unfmap(keys[m0 + tid]) + MARGIN;
    __syncthreads();

    unsigned abase = (unsigned)(m0 + w * 32 + srow) * DIM + scol;
    for (int kt = 0; kt < 8; ++kt) {
        int k0 = kbase + kt * 128;
        unsigned bbase = (unsigned)(k0 + w * 32 + srow) * DIM + scol;
        f32x4 acc[4][4];
        #pragma unroll
        for (int mi = 0; mi < 4; ++mi)
            #pragma unroll
            for (int ni = 0; ni < 4; ++ni)
                acc[mi][ni] = (f32x4){0.f, 0.f, 0.f, 0.f};

        for (int kb = 0; kb < DIM; kb += 32) {
            unsigned axoff = abase + kb;
            unsigned bxoff = bbase + kb;
            gload_lds16(xf + axoff,             &A[(w * 32) * 32]);
            gload_lds16(xf + axoff + 16u * DIM, &A[(w * 32 + 16) * 32]);
            gload_lds16(wf + bxoff,             &B[(w * 32) * 32]);
            gload_lds16(wf + bxoff + 16u * DIM, &B[(w * 32 + 16) * 32]);
            __syncthreads();
            half8 av[4], bv[4];
            #pragma unroll
            for (int mi = 0; mi < 4; ++mi)
                av[mi] = *(const half8*)&A[(wm + mi * 16 + lm) * 32 + sw];
            #pragma unroll
            for (int ni = 0; ni < 4; ++ni)
                bv[ni] = *(const half8*)&B[(wn + ni * 16 + lm) * 32 + sw];
            #pragma unroll
            for (int mi = 0; mi < 4; ++mi)
                #pragma unroll
                for (int ni = 0; ni < 4; ++ni)
                    acc[mi][ni] = __builtin_amdgcn_mfma_f32_16x16x32_f16(
                        av[mi], bv[ni], acc[mi][ni], 0, 0, 0);
            __syncthreads();
        }
        // emit candidates for this k-tile (rare; per-sample counters)
        float wsqv[4];
        #pragma unroll
        for (int ni = 0; ni < 4; ++ni) wsqv[ni] = wsq[k0 + wn + ni * 16 + lm];
        #pragma unroll
        for (int mi = 0; mi < 4; ++mi)
            #pragma unroll
            for (int r = 0; r < 4; ++r) {
                int rowi = wm + mi * 16 + quad * 4 + r;
                float thr = thr_l[rowi];
                #pragma unroll
                for (int ni = 0; ni < 4; ++ni) {
                    float sc = fmaf(-2.0f, acc[mi][ni][r], wsqv[ni]);
                    if (sc <= thr) {
                        unsigned int s = (unsigned int)(m0 + rowi);
                        unsigned int idx = atomicAdd(&cslot[s], 1u);
                        if (idx < SLOTS)
                            cand[s * SLOTS + idx] =
                                (unsigned int)(k0 + wn + ni * 16 + lm);
                    }
                }
            }
    }
}

// ---------------------------------------------------------------------------
// refine + scatter fused: one wave per sample.  Exact f32 dist^2 over its
// candidates with 2-way ILP (two independent load+reduce chains in flight);
// running u64 min (fmap(d)<<32)|k keeps first-index tie-break.  best is
// lane-uniform after the butterfly reduce; scatter directly:
// S[bmu][:] += x[s][:], cntf[bmu] += 1.
__global__ __launch_bounds__(256) void refine_scatter_kernel(
    const float* __restrict__ x, const float* __restrict__ w,
    const unsigned int* __restrict__ cand, const unsigned int* __restrict__ cslot,
    float* __restrict__ S, float* __restrict__ cntf) {
    int lane = threadIdx.x & 63;
    int s = blockIdx.x * 4 + (threadIdx.x >> 6);
    unsigned int n = cslot[s];
    if (n > SLOTS) n = SLOTS;
    float4 xv = *(const float4*)&x[(size_t)s * DIM + lane * 4];
    u64 best = ~0ULL;
    unsigned int c = 0;
    for (; c + 1 < n; c += 2) {
        unsigned int k0 = cand[(unsigned)s * SLOTS + c];
        unsigned int k1 = cand[(unsigned)s * SLOTS + c + 1];
        float4 wv0 = *(const float4*)&w[(size_t)k0 * DIM + lane * 4];
        float4 wv1 = *(const float4*)&w[(size_t)k1 * DIM + lane * 4];
        float dx0 = xv.x - wv0.x, dy0 = xv.y - wv0.y;
        float dz0 = xv.z - wv0.z, dw0 = xv.w - wv0.w;
        float dx1 = xv.x - wv1.x, dy1 = xv.y - wv1.y;
        float dz1 = xv.z - wv1.z, dw1 = xv.w - wv1.w;
        float d0 = dx0 * dx0 + dy0 * dy0 + dz0 * dz0 + dw0 * dw0;
        float d1 = dx1 * dx1 + dy1 * dy1 + dz1 * dz1 + dw1 * dw1;
        #pragma unroll
        for (int off = 32; off; off >>= 1) {
            d0 += __shfl_xor(d0, off, 64);
            d1 += __shfl_xor(d1, off, 64);
        }
        u64 key0 = ((u64)fmap(d0) << 32) | (u64)k0;
        u64 key1 = ((u64)fmap(d1) << 32) | (u64)k1;
        u64 kmin = (key0 < key1) ? key0 : key1;
        best = (kmin < best) ? kmin : best;
    }
    if (c < n) {
        unsigned int k0 = cand[(unsigned)s * SLOTS + c];
        float4 wv0 = *(const float4*)&w[(size_t)k0 * DIM + lane * 4];
        float dx0 = xv.x - wv0.x, dy0 = xv.y - wv0.y;
        float dz0 = xv.z - wv0.z, dw0 = xv.w - wv0.w;
        float d0 = dx0 * dx0 + dy0 * dy0 + dz0 * dz0 + dw0 * dw0;
        #pragma unroll
        for (int off = 32; off; off >>= 1) d0 += __shfl_xor(d0, off, 64);
        u64 key0 = ((u64)fmap(d0) << 32) | (u64)k0;
        best = (key0 < best) ? key0 : best;
    }
    unsigned int k = (unsigned int)best;   // n >= 1 always (seed-min row emits)
    float* Sp = &S[(size_t)k * DIM + lane * 4];
    atomicAdd(Sp + 0, xv.x);
    atomicAdd(Sp + 1, xv.y);
    atomicAdd(Sp + 2, xv.z);
    atomicAdd(Sp + 3, xv.w);
    if (lane == 0) atomicAdd(&cntf[k], 1.0f);
}

// ---------------------------------------------------------------------------
// gemm1: T[i][m] = sum_a G[i][a] * S[a][m], m in [0,32768), f32.
__global__ __launch_bounds__(256) void gemm1_kernel(
    const float* __restrict__ G, const float* __restrict__ S, float* __restrict__ T) {
    __shared__ float Sl[128 * 68];
    int n0 = blockIdx.x * 64;
    int tid = threadIdx.x;
    #pragma unroll
    for (int q = 0; q < 8; ++q) {
        int idx = q * 256 + tid;
        int row = idx >> 4, c4 = (idx & 15) * 4;
        *(float4*)&Sl[row * 68 + c4] = *(const float4*)&S[(size_t)row * 32768 + n0 + c4];
    }
    __syncthreads();
    int ng = tid & 15, ig = tid >> 4;
    for (int pass = 0; pass < 2; ++pass) {
        int ibase = pass * 64 + ig * 4;
        float acc[4][4] = {};
        for (int a = 0; a < 128; ++a) {
            float4 sv = *(const float4*)&Sl[a * 68 + ng * 4];
            #pragma unroll
            for (int ii = 0; ii < 4; ++ii) {
                float g = G[(ibase + ii) * 128 + a];
                acc[ii][0] = fmaf(g, sv.x, acc[ii][0]);
                acc[ii][1] = fmaf(g, sv.y, acc[ii][1]);
                acc[ii][2] = fmaf(g, sv.z, acc[ii][2]);
                acc[ii][3] = fmaf(g, sv.w, acc[ii][3]);
            }
        }
        #pragma unroll
        for (int ii = 0; ii < 4; ++ii)
            *(float4*)&T[(size_t)(ibase + ii) * 32768 + n0 + ng * 4] =
                *(float4*)&acc[ii][0];
    }
}

// ---------------------------------------------------------------------------
// gemm2 + inline denom + finalize:
//   P[i][b]   = sum_a G[i][a] * cntf[a][b]          (128 threads, LDS)
//   denom[j]  = sum_b P[i][b] * G[b][j]             (128 threads, LDS)
//   out[i][j][d] = (sum_b2 G[j][b2] T[i][b2*256+d]) / denom[j]
__global__ __launch_bounds__(256) void gemm2_fin_kernel(
    const float* __restrict__ G, const float* __restrict__ T,
    const float* __restrict__ cntf, const float* __restrict__ w,
    float* __restrict__ out) {
    __shared__ float Tl[128 * 68];
    __shared__ float Pl[128];
    __shared__ float dl[128];
    int i = blockIdx.x, dq = blockIdx.y;
    int tid = threadIdx.x;
    if (tid < 128) {
        float p = 0.f;
        for (int a = 0; a < 128; ++a)
            p = fmaf(G[i * 128 + a], cntf[a * 128 + tid], p);
        Pl[tid] = p;
    }
    #pragma unroll
    for (int q = 0; q < 8; ++q) {
        int idx = q * 256 + tid;
        int row = idx >> 4, c4 = (idx & 15) * 4;
        *(float4*)&Tl[row * 68 + c4] =
            *(const float4*)&T[(size_t)i * 32768 + row * 256 + dq * 64 + c4];
    }
    __syncthreads();
    if (tid < 128) {
        float accd = 0.f;
        for (int b2 = 0; b2 < 128; ++b2)
            accd = fmaf(Pl[b2], G[b2 * 128 + tid], accd);
        dl[tid] = accd;
    }
    __syncthreads();
    int dg = tid & 15, jg = tid >> 4;
    for (int pass = 0; pass < 2; ++pass) {
        int jbase = pass * 64 + jg * 4;
        float acc[4][4] = {};
        for (int b2 = 0; b2 < 128; ++b2) {
            float4 tv = *(const float4*)&Tl[b2 * 68 + dg * 4];
            #pragma unroll
            for (int jj = 0; jj < 4; ++jj) {
                float g = G[(jbase + jj) * 128 + b2];
                acc[jj][0] = fmaf(g, tv.x, acc[jj][0]);
                acc[jj][1] = fmaf(g, tv.y, acc[jj][1]);
                acc[jj][2] = fmaf(g, tv.z, acc[jj][2]);
                acc[jj][3] = fmaf(g, tv.w, acc[jj][3]);
            }
        }
        #pragma unroll
        for (int jj = 0; jj < 4; ++jj) {
            int j = jbase + jj;
            float dv = dl[j];
            size_t e = (size_t)(i * 128 + j) * DIM + dq * 64 + dg * 4;
            float4 r;
            if (dv != 0.0f) {
                float inv = 1.0f / dv;
                r.x = acc[jj][0] * inv; r.y = acc[jj][1] * inv;
                r.z = acc[jj][2] * inv; r.w = acc[jj][3] * inv;
            } else {
                r = *(const float4*)&w[e];
            }
            *(float4*)&out[e] = r;
        }
    }
}

// ---------------------------------------------------------------------------
extern "C" void kernel_launch(void* const* d_in, const int* in_sizes, int n_in,
                              void* d_out, int out_size, void* d_ws, size_t ws_size,
                              hipStream_t stream) {
    const float* data = (const float*)d_in[0];   // [8192, 256] f32
    const float* w    = (const float*)d_in[1];   // [128,128,256] f32
    const int*   itp  = (const int*)d_in[2];     // scalar
    float* out = (float*)d_out;                  // [128,128,256] f32

    char* ws = (char*)d_ws;
    size_t off = 0;
    float*        wsq   = (float*)(ws + off);        off += 65536;     //  64 KB
    unsigned int* keys  = (unsigned int*)(ws + off); off += 65536;     //  64 KB (u32 fmap seed scores)
    unsigned int* cslot = (unsigned int*)(ws + off); off += 65536;     //  64 KB (per-sample cand counters)
    float*        G     = (float*)(ws + off);        off += 65536;     //  64 KB [128][128]
    float*        cntf  = (float*)(ws + off);        off += 65536;     //  64 KB [a][b2]
    ushort*       xf    = (ushort*)(ws + off);       off += 4194304;   //   4 MB fp16 swizzled
    ushort*       wf    = (ushort*)(ws + off);       off += 8388608;   //   8 MB fp16 swizzled
    float*        S     = (float*)(ws + off);        off += 16777216;  //  16 MB [c][d]
    float*        T     = (float*)(ws + off);        off += 16777216;  //  16 MB [i][32768]
    // per-sample candidate slots alias T (8 MB of 16): T dead until gemm1,
    // cand dead after refine_scatter
    unsigned int* cand  = (unsigned int*)T;          // [BS][SLOTS] u32

    prep_kernel<<<(BS + KTOT) / 4, 256, 0, stream>>>(data, w, xf, wf, wsq,
                                                     S, G, cntf, keys, cslot, itp);
    bmu_seed_kernel<<<dim3(64, 16), 256, 0, stream>>>(xf, wf, wsq, keys);
    bmu_fused_kernel<<<dim3(64, 16), 256, 0, stream>>>(xf, wf, wsq, keys, cand, cslot);
    refine_scatter_kernel<<<BS / 4, 256, 0, stream>>>(data, w, cand, cslot, S, cntf);
    gemm1_kernel<<<512, 256, 0, stream>>>(G, S, T);
    gemm2_fin_kernel<<<dim3(128, 4), 256, 0, stream>>>(G, T, cntf, w, out);
}

// Round 17
// 321.707 us; speedup vs baseline: 1.0408x; 1.0408x over previous
//
#include <hip/hip_runtime.h>
#include <hip/hip_fp16.h>

// Problem constants
#define BS    8192
#define DIM   256
#define KTOT  16384      // 128x128 codebook
#define SLOTS 256        // candidate slots per sample (8 MB total, aliases T)
#define MARGIN 1.0f

typedef __attribute__((ext_vector_type(8))) _Float16 half8;
typedef __attribute__((ext_vector_type(4))) float f32x4;
typedef unsigned long long u64;

__device__ inline ushort f2h(float f) { return __half_as_ushort(__float2half(f)); }

// async global->LDS, 16B per lane; lds dest = wave-uniform base + lane*16
__device__ inline void gload_lds16(const void* g, void* l) {
    __builtin_amdgcn_global_load_lds(
        (const __attribute__((address_space(1))) unsigned int*)g,
        (__attribute__((address_space(3))) unsigned int*)l, 16, 0, 0);
}

// order-preserving f32 -> u32 map (ascending) and inverse
__device__ inline unsigned int fmap(float f) {
    unsigned int b = __float_as_uint(f);
    return (b & 0x80000000u) ? ~b : (b | 0x80000000u);
}
__device__ inline float unfmap(unsigned int m) {
    return (m & 0x80000000u) ? __uint_as_float(m & 0x7FFFFFFFu)
                             : __uint_as_float(~m);
}

// ---------------------------------------------------------------------------
// prep: merged setup + cvt.  Grid 6144 x 256 (rows 0..24575 == BS+KTOT).
//  - zero S (16 MB), G table, zero cntf, init keys(u32), zero cslot
//  - x,w -> fp16 with XOR-swizzled 32-half windows, + wsq for w rows
__global__ void prep_kernel(const float* __restrict__ x, const float* __restrict__ w,
                            ushort* __restrict__ xf, ushort* __restrict__ wf,
                            float* __restrict__ wsq, float* __restrict__ S,
                            float* __restrict__ G, float* __restrict__ cntf,
                            unsigned int* __restrict__ keys, unsigned int* __restrict__ cslot,
                            const int* __restrict__ itp) {
    int idx = blockIdx.x * 256 + threadIdx.x;
    if (idx < 1048576)     // 4M floats of S
        *(float4*)&S[(size_t)idx * 4] = make_float4(0.f, 0.f, 0.f, 0.f);
    if (idx < KTOT) {
        float itf = (float)itp[0];
        const float START_SIGMA = 64.0f;
        const float TAU = (float)(20.0 / 4.1588830833596715);  // 20 / ln(64)
        float sigma = START_SIGMA * expf(-itf / TAU);
        float d2 = 2.0f * sigma * sigma;
        int i = idx >> 7, j = idx & 127;
        float diff = (float)(i - j);
        G[idx] = expf(-(diff * diff) / d2);
        cntf[idx] = 0.f;
    }
    if (idx < BS) { keys[idx] = 0xFFFFFFFFu; cslot[idx] = 0u; }

    // cvt part: one wave per row
    int wid = threadIdx.x >> 6, lane = threadIdx.x & 63;
    int row = blockIdx.x * 4 + wid;           // 0 .. 24575 exactly
    int h = lane * 4;                         // half index 0..255
    int window = h >> 5, c = (h >> 3) & 3, off = h & 7;
    if (row < BS) {
        int swpos = (window << 5) + (((c ^ ((row >> 1) & 3)) << 3)) + off;
        float4 v = *(const float4*)&x[(size_t)row * DIM + h];
        ushort4 hv;
        hv.x = f2h(v.x); hv.y = f2h(v.y); hv.z = f2h(v.z); hv.w = f2h(v.w);
        *(ushort4*)&xf[(size_t)row * DIM + swpos] = hv;
    } else {
        int r = row - BS;
        int swpos = (window << 5) + (((c ^ ((r >> 1) & 3)) << 3)) + off;
        float4 v = *(const float4*)&w[(size_t)r * DIM + h];
        ushort4 hv;
        hv.x = f2h(v.x); hv.y = f2h(v.y); hv.z = f2h(v.z); hv.w = f2h(v.w);
        *(ushort4*)&wf[(size_t)r * DIM + swpos] = hv;
        float s = v.x * v.x + v.y * v.y + v.z * v.z + v.w * v.w;
        #pragma unroll
        for (int o = 32; o; o >>= 1) s += __shfl_down(s, o, 64);
        if (lane == 0) wsq[r] = s;
    }
}

// ---------------------------------------------------------------------------
// Seed pass: min over 2048 codebook rows (one 128-row k-tile per block at
// k0 = blockIdx.y*1024; grid (64,16)).  Tight threshold keeps the fused
// pass's emission volume (and its cost) minimal — measured optimum.
// Linear dispatch (measured better than XCD-chunked swizzle: 35 vs 113 MB).
// keys[s] = atomicMin of fmap(seed min).
__global__ __launch_bounds__(256) void bmu_seed_kernel(
    const ushort* __restrict__ xf, const ushort* __restrict__ wf,
    const float* __restrict__ wsq, unsigned int* __restrict__ keys) {
    __shared__ ushort A[128 * 32];   //  8 KB
    __shared__ ushort B[128 * 32];   //  8 KB
    __shared__ float red[128][2];

    int m0 = blockIdx.x * 128;
    int k0 = blockIdx.y * 1024;      // one kt tile: rows k0..k0+127
    int tid = threadIdx.x, w = tid >> 6, lane = tid & 63;
    int wm = (w & 1) * 64, wn = (w >> 1) * 64;
    int lm = lane & 15, quad = lane >> 4;
    int sw = (quad ^ ((lm >> 1) & 3)) * 8;
    int srow = lane >> 2, scol = (lane & 3) * 8;

    f32x4 acc[4][4];
    #pragma unroll
    for (int mi = 0; mi < 4; ++mi)
        #pragma unroll
        for (int ni = 0; ni < 4; ++ni)
            acc[mi][ni] = (f32x4){0.f, 0.f, 0.f, 0.f};

    unsigned abase = (unsigned)(m0 + w * 32 + srow) * DIM + scol;
    unsigned bbase = (unsigned)(k0 + w * 32 + srow) * DIM + scol;
    for (int kb = 0; kb < DIM; kb += 32) {
        unsigned axoff = abase + kb;
        unsigned bxoff = bbase + kb;
        gload_lds16(xf + axoff,             &A[(w * 32) * 32]);
        gload_lds16(xf + axoff + 16u * DIM, &A[(w * 32 + 16) * 32]);
        gload_lds16(wf + bxoff,             &B[(w * 32) * 32]);
        gload_lds16(wf + bxoff + 16u * DIM, &B[(w * 32 + 16) * 32]);
        __syncthreads();
        half8 av[4], bv[4];
        #pragma unroll
        for (int mi = 0; mi < 4; ++mi)
            av[mi] = *(const half8*)&A[(wm + mi * 16 + lm) * 32 + sw];
        #pragma unroll
        for (int ni = 0; ni < 4; ++ni)
            bv[ni] = *(const half8*)&B[(wn + ni * 16 + lm) * 32 + sw];
        #pragma unroll
        for (int mi = 0; mi < 4; ++mi)
            #pragma unroll
            for (int ni = 0; ni < 4; ++ni)
                acc[mi][ni] = __builtin_amdgcn_mfma_f32_16x16x32_f16(
                    av[mi], bv[ni], acc[mi][ni], 0, 0, 0);
        __syncthreads();
    }
    float wsqv[4];
    #pragma unroll
    for (int ni = 0; ni < 4; ++ni) wsqv[ni] = wsq[k0 + wn + ni * 16 + lm];
    #pragma unroll
    for (int mi = 0; mi < 4; ++mi)
        #pragma unroll
        for (int r = 0; r < 4; ++r) {
            float b = 3.4e38f;
            #pragma unroll
            for (int ni = 0; ni < 4; ++ni)
                b = fminf(b, fmaf(-2.0f, acc[mi][ni][r], wsqv[ni]));
            #pragma unroll
            for (int mask = 1; mask < 16; mask <<= 1)
                b = fminf(b, __shfl_xor(b, mask, 64));
            if (lm == 0) red[wm + mi * 16 + quad * 4 + r][w >> 1] = b;
        }
    __syncthreads();
    if (tid < 128)
        atomicMin(&keys[m0 + tid], fmap(fminf(red[tid][0], red[tid][1])));
}

// ---------------------------------------------------------------------------
// Main fused pass: single full fp16 GEMM (2-barrier 32-K steps — the proven
// best structure).  Grid (64, 16): 8 k-tiles/block, 1024 blocks = 4/CU.
// thr = seed(keys) + MARGIN in a 128-entry LDS table.  Emission: per-SAMPLE
// slot arrays -- atomicAdd on cslot[s] (8192 counters, no line contention),
// bare u32 k payload at cand[s*SLOTS+idx].
__global__ __launch_bounds__(256) void bmu_fused_kernel(
    const ushort* __restrict__ xf, const ushort* __restrict__ wf,
    const float* __restrict__ wsq, const unsigned int* __restrict__ keys,
    unsigned int* __restrict__ cand, unsigned int* __restrict__ cslot) {
    __shared__ ushort A[128 * 32];   //  8 KB
    __shared__ ushort B[128 * 32];   //  8 KB
    __shared__ float thr_l[128];     //  0.5 KB per-row thresholds

    int m0 = blockIdx.x * 128;
    int kbase = blockIdx.y * 1024;   // 8 k-tiles per block
    int tid = threadIdx.x, w = tid >> 6, lane = tid & 63;
    int wm = (w & 1) * 64, wn = (w >> 1) * 64;
    int lm = lane & 15, quad = lane >> 4;
    int sw = (quad ^ ((lm >> 1) & 3)) * 8;
    int srow = lane >> 2, scol = (lane & 3) * 8;

    if (tid < 128) thr_l[tid] = unfmap(keys[m0 + tid]) + MARGIN;
    __syncthreads();

    unsigned abase = (unsigned)(m0 + w * 32 + srow) * DIM + scol;
    for (int kt = 0; kt < 8; ++kt) {
        int k0 = kbase + kt * 128;
        unsigned bbase = (unsigned)(k0 + w * 32 + srow) * DIM + scol;
        f32x4 acc[4][4];
        #pragma unroll
        for (int mi = 0; mi < 4; ++mi)
            #pragma unroll
            for (int ni = 0; ni < 4; ++ni)
                acc[mi][ni] = (f32x4){0.f, 0.f, 0.f, 0.f};

        for (int kb = 0; kb < DIM; kb += 32) {
            unsigned axoff = abase + kb;
            unsigned bxoff = bbase + kb;
            gload_lds16(xf + axoff,             &A[(w * 32) * 32]);
            gload_lds16(xf + axoff + 16u * DIM, &A[(w * 32 + 16) * 32]);
            gload_lds16(wf + bxoff,             &B[(w * 32) * 32]);
            gload_lds16(wf + bxoff + 16u * DIM, &B[(w * 32 + 16) * 32]);
            __syncthreads();
            half8 av[4], bv[4];
            #pragma unroll
            for (int mi = 0; mi < 4; ++mi)
                av[mi] = *(const half8*)&A[(wm + mi * 16 + lm) * 32 + sw];
            #pragma unroll
            for (int ni = 0; ni < 4; ++ni)
                bv[ni] = *(const half8*)&B[(wn + ni * 16 + lm) * 32 + sw];
            #pragma unroll
            for (int mi = 0; mi < 4; ++mi)
                #pragma unroll
                for (int ni = 0; ni < 4; ++ni)
                    acc[mi][ni] = __builtin_amdgcn_mfma_f32_16x16x32_f16(
                        av[mi], bv[ni], acc[mi][ni], 0, 0, 0);
            __syncthreads();
        }
        // emit candidates for this k-tile (rare; per-sample counters)
        float wsqv[4];
        #pragma unroll
        for (int ni = 0; ni < 4; ++ni) wsqv[ni] = wsq[k0 + wn + ni * 16 + lm];
        #pragma unroll
        for (int mi = 0; mi < 4; ++mi)
            #pragma unroll
            for (int r = 0; r < 4; ++r) {
                int rowi = wm + mi * 16 + quad * 4 + r;
                float thr = thr_l[rowi];
                #pragma unroll
                for (int ni = 0; ni < 4; ++ni) {
                    float sc = fmaf(-2.0f, acc[mi][ni][r], wsqv[ni]);
                    if (sc <= thr) {
                        unsigned int s = (unsigned int)(m0 + rowi);
                        unsigned int idx = atomicAdd(&cslot[s], 1u);
                        if (idx < SLOTS)
                            cand[s * SLOTS + idx] =
                                (unsigned int)(k0 + wn + ni * 16 + lm);
                    }
                }
            }
    }
}

// ---------------------------------------------------------------------------
// refine + scatter fused: one wave per sample.  Exact f32 dist^2 over its
// candidates with 2-way ILP (two independent load+reduce chains in flight);
// running u64 min (fmap(d)<<32)|k keeps first-index tie-break.  best is
// lane-uniform after the butterfly reduce; scatter directly:
// S[bmu][:] += x[s][:], cntf[bmu] += 1.
__global__ __launch_bounds__(256) void refine_scatter_kernel(
    const float* __restrict__ x, const float* __restrict__ w,
    const unsigned int* __restrict__ cand, const unsigned int* __restrict__ cslot,
    float* __restrict__ S, float* __restrict__ cntf) {
    int lane = threadIdx.x & 63;
    int s = blockIdx.x * 4 + (threadIdx.x >> 6);
    unsigned int n = cslot[s];
    if (n > SLOTS) n = SLOTS;
    float4 xv = *(const float4*)&x[(size_t)s * DIM + lane * 4];
    u64 best = ~0ULL;
    unsigned int c = 0;
    for (; c + 1 < n; c += 2) {
        unsigned int k0 = cand[(unsigned)s * SLOTS + c];
        unsigned int k1 = cand[(unsigned)s * SLOTS + c + 1];
        float4 wv0 = *(const float4*)&w[(size_t)k0 * DIM + lane * 4];
        float4 wv1 = *(const float4*)&w[(size_t)k1 * DIM + lane * 4];
        float dx0 = xv.x - wv0.x, dy0 = xv.y - wv0.y;
        float dz0 = xv.z - wv0.z, dw0 = xv.w - wv0.w;
        float dx1 = xv.x - wv1.x, dy1 = xv.y - wv1.y;
        float dz1 = xv.z - wv1.z, dw1 = xv.w - wv1.w;
        float d0 = dx0 * dx0 + dy0 * dy0 + dz0 * dz0 + dw0 * dw0;
        float d1 = dx1 * dx1 + dy1 * dy1 + dz1 * dz1 + dw1 * dw1;
        #pragma unroll
        for (int off = 32; off; off >>= 1) {
            d0 += __shfl_xor(d0, off, 64);
            d1 += __shfl_xor(d1, off, 64);
        }
        u64 key0 = ((u64)fmap(d0) << 32) | (u64)k0;
        u64 key1 = ((u64)fmap(d1) << 32) | (u64)k1;
        u64 kmin = (key0 < key1) ? key0 : key1;
        best = (kmin < best) ? kmin : best;
    }
    if (c < n) {
        unsigned int k0 = cand[(unsigned)s * SLOTS + c];
        float4 wv0 = *(const float4*)&w[(size_t)k0 * DIM + lane * 4];
        float dx0 = xv.x - wv0.x, dy0 = xv.y - wv0.y;
        float dz0 = xv.z - wv0.z, dw0 = xv.w - wv0.w;
        float d0 = dx0 * dx0 + dy0 * dy0 + dz0 * dz0 + dw0 * dw0;
        #pragma unroll
        for (int off = 32; off; off >>= 1) d0 += __shfl_xor(d0, off, 64);
        u64 key0 = ((u64)fmap(d0) << 32) | (u64)k0;
        best = (key0 < best) ? key0 : best;
    }
    unsigned int k = (unsigned int)best;   // n >= 1 always (seed-min row emits)
    float* Sp = &S[(size_t)k * DIM + lane * 4];
    atomicAdd(Sp + 0, xv.x);
    atomicAdd(Sp + 1, xv.y);
    atomicAdd(Sp + 2, xv.z);
    atomicAdd(Sp + 3, xv.w);
    if (lane == 0) atomicAdd(&cntf[k], 1.0f);
}

// ---------------------------------------------------------------------------
// gemm1: T[i][m] = sum_a G[i][a] * S[a][m], m in [0,32768), f32.
__global__ __launch_bounds__(256) void gemm1_kernel(
    const float* __restrict__ G, const float* __restrict__ S, float* __restrict__ T) {
    __shared__ float Sl[128 * 68];
    int n0 = blockIdx.x * 64;
    int tid = threadIdx.x;
    #pragma unroll
    for (int q = 0; q < 8; ++q) {
        int idx = q * 256 + tid;
        int row = idx >> 4, c4 = (idx & 15) * 4;
        *(float4*)&Sl[row * 68 + c4] = *(const float4*)&S[(size_t)row * 32768 + n0 + c4];
    }
    __syncthreads();
    int ng = tid & 15, ig = tid >> 4;
    for (int pass = 0; pass < 2; ++pass) {
        int ibase = pass * 64 + ig * 4;
        float acc[4][4] = {};
        for (int a = 0; a < 128; ++a) {
            float4 sv = *(const float4*)&Sl[a * 68 + ng * 4];
            #pragma unroll
            for (int ii = 0; ii < 4; ++ii) {
                float g = G[(ibase + ii) * 128 + a];
                acc[ii][0] = fmaf(g, sv.x, acc[ii][0]);
                acc[ii][1] = fmaf(g, sv.y, acc[ii][1]);
                acc[ii][2] = fmaf(g, sv.z, acc[ii][2]);
                acc[ii][3] = fmaf(g, sv.w, acc[ii][3]);
            }
        }
        #pragma unroll
        for (int ii = 0; ii < 4; ++ii)
            *(float4*)&T[(size_t)(ibase + ii) * 32768 + n0 + ng * 4] =
                *(float4*)&acc[ii][0];
    }
}

// ---------------------------------------------------------------------------
// gemm2 + inline denom + finalize:
//   P[i][b]   = sum_a G[i][a] * cntf[a][b]          (128 threads, LDS)
//   denom[j]  = sum_b P[i][b] * G[b][j]             (128 threads, LDS)
//   out[i][j][d] = (sum_b2 G[j][b2] T[i][b2*256+d]) / denom[j]
__global__ __launch_bounds__(256) void gemm2_fin_kernel(
    const float* __restrict__ G, const float* __restrict__ T,
    const float* __restrict__ cntf, const float* __restrict__ w,
    float* __restrict__ out) {
    __shared__ float Tl[128 * 68];
    __shared__ float Pl[128];
    __shared__ float dl[128];
    int i = blockIdx.x, dq = blockIdx.y;
    int tid = threadIdx.x;
    if (tid < 128) {
        float p = 0.f;
        for (int a = 0; a < 128; ++a)
            p = fmaf(G[i * 128 + a], cntf[a * 128 + tid], p);
        Pl[tid] = p;
    }
    #pragma unroll
    for (int q = 0; q < 8; ++q) {
        int idx = q * 256 + tid;
        int row = idx >> 4, c4 = (idx & 15) * 4;
        *(float4*)&Tl[row * 68 + c4] =
            *(const float4*)&T[(size_t)i * 32768 + row * 256 + dq * 64 + c4];
    }
    __syncthreads();
    if (tid < 128) {
        float accd = 0.f;
        for (int b2 = 0; b2 < 128; ++b2)
            accd = fmaf(Pl[b2], G[b2 * 128 + tid], accd);
        dl[tid] = accd;
    }
    __syncthreads();
    int dg = tid & 15, jg = tid >> 4;
    for (int pass = 0; pass < 2; ++pass) {
        int jbase = pass * 64 + jg * 4;
        float acc[4][4] = {};
        for (int b2 = 0; b2 < 128; ++b2) {
            float4 tv = *(const float4*)&Tl[b2 * 68 + dg * 4];
            #pragma unroll
            for (int jj = 0; jj < 4; ++jj) {
                float g = G[(jbase + jj) * 128 + b2];
                acc[jj][0] = fmaf(g, tv.x, acc[jj][0]);
                acc[jj][1] = fmaf(g, tv.y, acc[jj][1]);
                acc[jj][2] = fmaf(g, tv.z, acc[jj][2]);
                acc[jj][3] = fmaf(g, tv.w, acc[jj][3]);
            }
        }
        #pragma unroll
        for (int jj = 0; jj < 4; ++jj) {
            int j = jbase + jj;
            float dv = dl[j];
            size_t e = (size_t)(i * 128 + j) * DIM + dq * 64 + dg * 4;
            float4 r;
            if (dv != 0.0f) {
                float inv = 1.0f / dv;
                r.x = acc[jj][0] * inv; r.y = acc[jj][1] * inv;
                r.z = acc[jj][2] * inv; r.w = acc[jj][3] * inv;
            } else {
                r = *(const float4*)&w[e];
            }
            *(float4*)&out[e] = r;
        }
    }
}

// ---------------------------------------------------------------------------
extern "C" void kernel_launch(void* const* d_in, const int* in_sizes, int n_in,
                              void* d_out, int out_size, void* d_ws, size_t ws_size,
                              hipStream_t stream) {
    const float* data = (const float*)d_in[0];   // [8192, 256] f32
    const float* w    = (const float*)d_in[1];   // [128,128,256] f32
    const int*   itp  = (const int*)d_in[2];     // scalar
    float* out = (float*)d_out;                  // [128,128,256] f32

    char* ws = (char*)d_ws;
    size_t off = 0;
    float*        wsq   = (float*)(ws + off);        off += 65536;     //  64 KB
    unsigned int* keys  = (unsigned int*)(ws + off); off += 65536;     //  64 KB (u32 fmap seed scores)
    unsigned int* cslot = (unsigned int*)(ws + off); off += 65536;     //  64 KB (per-sample cand counters)
    float*        G     = (float*)(ws + off);        off += 65536;     //  64 KB [128][128]
    float*        cntf  = (float*)(ws + off);        off += 65536;     //  64 KB [a][b2]
    ushort*       xf    = (ushort*)(ws + off);       off += 4194304;   //   4 MB fp16 swizzled
    ushort*       wf    = (ushort*)(ws + off);       off += 8388608;   //   8 MB fp16 swizzled
    float*        S     = (float*)(ws + off);        off += 16777216;  //  16 MB [c][d]
    float*        T     = (float*)(ws + off);        off += 16777216;  //  16 MB [i][32768]
    // per-sample candidate slots alias T (8 MB of 16): T dead until gemm1,
    // cand dead after refine_scatter
    unsigned int* cand  = (unsigned int*)T;          // [BS][SLOTS] u32

    prep_kernel<<<(BS + KTOT) / 4, 256, 0, stream>>>(data, w, xf, wf, wsq,
                                                     S, G, cntf, keys, cslot, itp);
    bmu_seed_kernel<<<dim3(64, 16), 256, 0, stream>>>(xf, wf, wsq, keys);
    bmu_fused_kernel<<<dim3(64, 16), 256, 0, stream>>>(xf, wf, wsq, keys, cand, cslot);
    refine_scatter_kernel<<<BS / 4, 256, 0, stream>>>(data, w, cand, cslot, S, cntf);
    gemm1_kernel<<<512, 256, 0, stream>>>(G, S, T);
    gemm2_fin_kernel<<<dim3(128, 4), 256, 0, stream>>>(G, T, cntf, w, out);
}